// Round 1
// baseline (79.702 us; speedup 1.0000x reference)
//
#include <hip/hip_runtime.h>
#include <math.h>

#define VOCAB   100000
#define DIM     256
#define BATCH   16384
#define CTX     20
#define NUM_NEG 5
#define ALPHA   0.5f
#define EPS     1e-6f

#define WAVES_PER_BLOCK 4
#define NBLOCKS (BATCH / WAVES_PER_BLOCK)   // 4096

__device__ __forceinline__ float wave_reduce_sum(float v) {
    #pragma unroll
    for (int off = 32; off > 0; off >>= 1)
        v += __shfl_xor(v, off, 64);
    return v;
}

__global__ __launch_bounds__(256) void orphic_main(
    const int*   __restrict__ tgt,
    const int*   __restrict__ ctx,
    const int*   __restrict__ neg,
    const float* __restrict__ freq,
    const float* __restrict__ Wf,
    const float* __restrict__ Wr,
    const float* __restrict__ Wi,
    float*       __restrict__ partial)   // [NBLOCKS][2]
{
    const int wave = threadIdx.x >> 6;          // 0..3
    const int lane = threadIdx.x & 63;
    const int b    = blockIdx.x * WAVES_PER_BLOCK + wave;

    // ---- build orphic[b] : this lane's 4 dims ----
    const int t = tgt[b];
    const float4 f = *(const float4*)(Wf + (size_t)t * DIM + lane * 4);
    const float4 r = *(const float4*)(Wr + (size_t)t * DIM + lane * 4);
    const float4 w = *(const float4*)(Wi + (size_t)t * DIM + lane * 4);
    const float sc = 1.0f / (1.0f + logf(freq[t] + EPS));
    float4 o;
    o.x = ALPHA * f.x + (1.0f - ALPHA) * r.x + w.x * sc;
    o.y = ALPHA * f.y + (1.0f - ALPHA) * r.y + w.y * sc;
    o.z = ALPHA * f.z + (1.0f - ALPHA) * r.z + w.z * sc;
    o.w = ALPHA * f.w + (1.0f - ALPHA) * r.w + w.w * sc;

    // ---- positive scores ----
    float pos_part = 0.0f;
    #pragma unroll 4
    for (int c = 0; c < CTX; ++c) {
        const int tok = ctx[(size_t)b * CTX + c];
        const float4 e = *(const float4*)(Wf + (size_t)tok * DIM + lane * 4);
        float d = o.x * e.x + o.y * e.y + o.z * e.z + o.w * e.w;
        float s = wave_reduce_sum(d);
        // -log(sigmoid(s) + eps)
        pos_part += -logf(1.0f / (1.0f + expf(-s)) + EPS);
    }

    // ---- negative scores ----
    float neg_part = 0.0f;
    #pragma unroll
    for (int k = 0; k < NUM_NEG; ++k) {
        const int tok = neg[(size_t)b * NUM_NEG + k];
        const float4 e = *(const float4*)(Wf + (size_t)tok * DIM + lane * 4);
        float d = o.x * e.x + o.y * e.y + o.z * e.z + o.w * e.w;
        float s = wave_reduce_sum(d);
        // -log(sigmoid(-s) + eps)
        neg_part += -logf(1.0f / (1.0f + expf(s)) + EPS);
    }
    neg_part *= (1.0f / NUM_NEG);   // per-sample mean over K

    // ---- block reduce (4 waves) ----
    __shared__ float sp[WAVES_PER_BLOCK];
    __shared__ float sn[WAVES_PER_BLOCK];
    if (lane == 0) { sp[wave] = pos_part; sn[wave] = neg_part; }
    __syncthreads();
    if (threadIdx.x == 0) {
        partial[(size_t)blockIdx.x * 2 + 0] = sp[0] + sp[1] + sp[2] + sp[3];
        partial[(size_t)blockIdx.x * 2 + 1] = sn[0] + sn[1] + sn[2] + sn[3];
    }
}

__global__ __launch_bounds__(256) void orphic_reduce(
    const float* __restrict__ partial, float* __restrict__ out)
{
    double p = 0.0, n = 0.0;
    for (int i = threadIdx.x; i < NBLOCKS; i += 256) {
        p += (double)partial[(size_t)i * 2 + 0];
        n += (double)partial[(size_t)i * 2 + 1];
    }
    __shared__ double lp[256];
    __shared__ double ln[256];
    lp[threadIdx.x] = p;
    ln[threadIdx.x] = n;
    __syncthreads();
    for (int s = 128; s > 0; s >>= 1) {
        if (threadIdx.x < s) {
            lp[threadIdx.x] += lp[threadIdx.x + s];
            ln[threadIdx.x] += ln[threadIdx.x + s];
        }
        __syncthreads();
    }
    if (threadIdx.x == 0) {
        out[0] = (float)(lp[0] / (double)((size_t)BATCH * CTX) + ln[0]);
    }
}

extern "C" void kernel_launch(void* const* d_in, const int* in_sizes, int n_in,
                              void* d_out, int out_size, void* d_ws, size_t ws_size,
                              hipStream_t stream) {
    const int*   tgt  = (const int*)  d_in[0];
    const int*   ctx  = (const int*)  d_in[1];
    const int*   neg  = (const int*)  d_in[2];
    const float* freq = (const float*)d_in[3];
    const float* Wf   = (const float*)d_in[4];
    const float* Wr   = (const float*)d_in[5];
    const float* Wi   = (const float*)d_in[6];
    float* out = (float*)d_out;
    float* partial = (float*)d_ws;   // NBLOCKS*2 floats = 32 KB

    orphic_main<<<NBLOCKS, 256, 0, stream>>>(tgt, ctx, neg, freq, Wf, Wr, Wi, partial);
    orphic_reduce<<<1, 256, 0, stream>>>(partial, out);
}

// Round 2
// 74.402 us; speedup vs baseline: 1.0712x; 1.0712x over previous
//
#include <hip/hip_runtime.h>
#include <math.h>

#define VOCAB   100000
#define DIM     256
#define BATCH   16384
#define CTX     20
#define NUM_NEG 5
#define NTOK    (CTX + NUM_NEG)     // 25
#define ALPHA   0.5f
#define EPS     1e-6f

#define WAVES_PER_BLOCK 4
#define NBLOCKS (BATCH / WAVES_PER_BLOCK)   // 4096

__global__ __launch_bounds__(256) void orphic_main(
    const int*   __restrict__ tgt,
    const int*   __restrict__ ctx,
    const int*   __restrict__ neg,
    const float* __restrict__ freq,
    const float* __restrict__ Wf,
    const float* __restrict__ Wr,
    const float* __restrict__ Wi,
    float*       __restrict__ partial)   // [NBLOCKS][2]
{
    const int wave = threadIdx.x >> 6;          // 0..3
    const int lane = threadIdx.x & 63;
    const int g    = lane >> 4;                 // score-group 0..3
    const int q    = lane & 15;                 // dim-slot within group
    const int b    = blockIdx.x * WAVES_PER_BLOCK + wave;

    // ---- build orphic[b], dims [q*16, q*16+16) as 4 float4 ----
    const int t = tgt[b];
    const float* ft = Wf + (size_t)t * DIM + q * 16;
    const float* rt = Wr + (size_t)t * DIM + q * 16;
    const float* it_ = Wi + (size_t)t * DIM + q * 16;
    float4 f0 = *(const float4*)(ft + 0),  f1 = *(const float4*)(ft + 4);
    float4 f2 = *(const float4*)(ft + 8),  f3 = *(const float4*)(ft + 12);
    float4 r0 = *(const float4*)(rt + 0),  r1 = *(const float4*)(rt + 4);
    float4 r2 = *(const float4*)(rt + 8),  r3 = *(const float4*)(rt + 12);
    float4 w0 = *(const float4*)(it_ + 0), w1 = *(const float4*)(it_ + 4);
    float4 w2 = *(const float4*)(it_ + 8), w3 = *(const float4*)(it_ + 12);
    const float sc = 1.0f / (1.0f + logf(freq[t] + EPS));

    float4 o0, o1, o2, o3;
    o0.x = ALPHA*f0.x + (1.0f-ALPHA)*r0.x + w0.x*sc;
    o0.y = ALPHA*f0.y + (1.0f-ALPHA)*r0.y + w0.y*sc;
    o0.z = ALPHA*f0.z + (1.0f-ALPHA)*r0.z + w0.z*sc;
    o0.w = ALPHA*f0.w + (1.0f-ALPHA)*r0.w + w0.w*sc;
    o1.x = ALPHA*f1.x + (1.0f-ALPHA)*r1.x + w1.x*sc;
    o1.y = ALPHA*f1.y + (1.0f-ALPHA)*r1.y + w1.y*sc;
    o1.z = ALPHA*f1.z + (1.0f-ALPHA)*r1.z + w1.z*sc;
    o1.w = ALPHA*f1.w + (1.0f-ALPHA)*r1.w + w1.w*sc;
    o2.x = ALPHA*f2.x + (1.0f-ALPHA)*r2.x + w2.x*sc;
    o2.y = ALPHA*f2.y + (1.0f-ALPHA)*r2.y + w2.y*sc;
    o2.z = ALPHA*f2.z + (1.0f-ALPHA)*r2.z + w2.z*sc;
    o2.w = ALPHA*f2.w + (1.0f-ALPHA)*r2.w + w2.w*sc;
    o3.x = ALPHA*f3.x + (1.0f-ALPHA)*r3.x + w3.x*sc;
    o3.y = ALPHA*f3.y + (1.0f-ALPHA)*r3.y + w3.y*sc;
    o3.z = ALPHA*f3.z + (1.0f-ALPHA)*r3.z + w3.z*sc;
    o3.w = ALPHA*f3.w + (1.0f-ALPHA)*r3.w + w3.w*sc;

    // ---- all 25 token indices, coalesced, one per lane ----
    int tok = 0;
    if (lane < CTX)       tok = ctx[(size_t)b * CTX + lane];
    else if (lane < NTOK) tok = neg[(size_t)b * NUM_NEG + (lane - CTX)];

    float posacc = 0.0f, negacc = 0.0f;

    // 7 iterations x 4 groups cover tokens j = it*4+g; tail (j>=25) clamped+masked
    #pragma unroll 2
    for (int it = 0; it < 7; ++it) {
        int j = it * 4 + g;
        const bool valid = (j < NTOK);
        const int jc = valid ? j : (NTOK - 1);
        const int tj = __shfl(tok, jc, 64);

        const float* e = Wf + (size_t)tj * DIM + q * 16;
        float4 e0 = *(const float4*)(e + 0),  e1 = *(const float4*)(e + 4);
        float4 e2 = *(const float4*)(e + 8),  e3 = *(const float4*)(e + 12);

        float d = o0.x*e0.x + o0.y*e0.y + o0.z*e0.z + o0.w*e0.w
                + o1.x*e1.x + o1.y*e1.y + o1.z*e1.z + o1.w*e1.w
                + o2.x*e2.x + o2.y*e2.y + o2.z*e2.z + o2.w*e2.w
                + o3.x*e3.x + o3.y*e3.y + o3.z*e3.z + o3.w*e3.w;

        d += __shfl_xor(d, 1, 64);
        d += __shfl_xor(d, 2, 64);
        d += __shfl_xor(d, 4, 64);
        d += __shfl_xor(d, 8, 64);   // all 16 lanes of group hold the dot

        const float sgn = (jc < CTX) ? -1.0f : 1.0f;   // pos: exp(-s), neg: exp(+s)
        const float loss = -logf(1.0f / (1.0f + expf(sgn * d)) + EPS);
        if (valid) {
            if (jc < CTX) posacc += loss;
            else          negacc += loss;
        }
    }
    negacc *= (1.0f / NUM_NEG);

    // ---- wave reduce: one representative lane (q==0) per group ----
    float p = (q == 0) ? posacc : 0.0f;
    float n = (q == 0) ? negacc : 0.0f;
    p += __shfl_xor(p, 16, 64);  p += __shfl_xor(p, 32, 64);
    n += __shfl_xor(n, 16, 64);  n += __shfl_xor(n, 32, 64);

    __shared__ float sp[WAVES_PER_BLOCK];
    __shared__ float sn[WAVES_PER_BLOCK];
    if (lane == 0) { sp[wave] = p; sn[wave] = n; }
    __syncthreads();
    if (threadIdx.x == 0) {
        partial[(size_t)blockIdx.x * 2 + 0] = sp[0] + sp[1] + sp[2] + sp[3];
        partial[(size_t)blockIdx.x * 2 + 1] = sn[0] + sn[1] + sn[2] + sn[3];
    }
}

__global__ __launch_bounds__(256) void orphic_reduce(
    const float* __restrict__ partial, float* __restrict__ out)
{
    double p = 0.0, n = 0.0;
    for (int i = threadIdx.x; i < NBLOCKS; i += 256) {
        p += (double)partial[(size_t)i * 2 + 0];
        n += (double)partial[(size_t)i * 2 + 1];
    }
    __shared__ double lp[256];
    __shared__ double ln[256];
    lp[threadIdx.x] = p;
    ln[threadIdx.x] = n;
    __syncthreads();
    for (int s = 128; s > 0; s >>= 1) {
        if (threadIdx.x < s) {
            lp[threadIdx.x] += lp[threadIdx.x + s];
            ln[threadIdx.x] += ln[threadIdx.x + s];
        }
        __syncthreads();
    }
    if (threadIdx.x == 0) {
        out[0] = (float)(lp[0] / (double)((size_t)BATCH * CTX) + ln[0]);
    }
}

extern "C" void kernel_launch(void* const* d_in, const int* in_sizes, int n_in,
                              void* d_out, int out_size, void* d_ws, size_t ws_size,
                              hipStream_t stream) {
    const int*   tgt  = (const int*)  d_in[0];
    const int*   ctx  = (const int*)  d_in[1];
    const int*   neg  = (const int*)  d_in[2];
    const float* freq = (const float*)d_in[3];
    const float* Wf   = (const float*)d_in[4];
    const float* Wr   = (const float*)d_in[5];
    const float* Wi   = (const float*)d_in[6];
    float* out = (float*)d_out;
    float* partial = (float*)d_ws;   // NBLOCKS*2 floats = 32 KB

    orphic_main<<<NBLOCKS, 256, 0, stream>>>(tgt, ctx, neg, freq, Wf, Wr, Wi, partial);
    orphic_reduce<<<1, 256, 0, stream>>>(partial, out);
}

// Round 3
// 53.020 us; speedup vs baseline: 1.5032x; 1.4033x over previous
//
#include <hip/hip_runtime.h>
#include <hip/hip_fp8.h>
#include <math.h>

#define VOCAB   100000
#define DIM     256
#define BATCH   16384
#define CTX     20
#define NUM_NEG 5
#define NTOK    (CTX + NUM_NEG)     // 25
#define ALPHA   0.5f
#define EPS     1e-6f
#define SCALE     512.0f
#define INV_SCALE (1.0f / 512.0f)

#define WAVES_PER_BLOCK 4
#define NBLOCKS (BATCH / WAVES_PER_BLOCK)   // 4096

#if __has_builtin(__builtin_amdgcn_cvt_pk_f32_fp8) && __has_builtin(__builtin_amdgcn_cvt_pk_fp8_f32)
#define HW_FP8 1
typedef float v2f __attribute__((ext_vector_type(2)));
#else
#define HW_FP8 0
#endif

// ---------------- convert W_fwd (f32) -> fp8 e4m3 (x512) ----------------
__global__ __launch_bounds__(256) void convert_wf(
    const float* __restrict__ Wf, uint4* __restrict__ wf8)
{
    // one thread per 16 elements: read 4 float4 (64B), write uint4 (16B)
    const size_t t = (size_t)blockIdx.x * 256 + threadIdx.x;   // < VOCAB*DIM/16
    const float4* src = (const float4*)Wf + t * 4;
    float4 a = src[0], b = src[1], c = src[2], d = src[3];
    unsigned int r0, r1, r2, r3;
#if HW_FP8
    r0 = (unsigned)__builtin_amdgcn_cvt_pk_fp8_f32(a.x*SCALE, a.y*SCALE, 0, false);
    r0 = (unsigned)__builtin_amdgcn_cvt_pk_fp8_f32(a.z*SCALE, a.w*SCALE, (int)r0, true);
    r1 = (unsigned)__builtin_amdgcn_cvt_pk_fp8_f32(b.x*SCALE, b.y*SCALE, 0, false);
    r1 = (unsigned)__builtin_amdgcn_cvt_pk_fp8_f32(b.z*SCALE, b.w*SCALE, (int)r1, true);
    r2 = (unsigned)__builtin_amdgcn_cvt_pk_fp8_f32(c.x*SCALE, c.y*SCALE, 0, false);
    r2 = (unsigned)__builtin_amdgcn_cvt_pk_fp8_f32(c.z*SCALE, c.w*SCALE, (int)r2, true);
    r3 = (unsigned)__builtin_amdgcn_cvt_pk_fp8_f32(d.x*SCALE, d.y*SCALE, 0, false);
    r3 = (unsigned)__builtin_amdgcn_cvt_pk_fp8_f32(d.z*SCALE, d.w*SCALE, (int)r3, true);
#else
    {
        const float v[16] = {a.x,a.y,a.z,a.w,b.x,b.y,b.z,b.w,c.x,c.y,c.z,c.w,d.x,d.y,d.z,d.w};
        unsigned int rr[4] = {0,0,0,0};
        for (int i = 0; i < 16; ++i) {
            unsigned int byte = (unsigned int)__hip_cvt_float_to_fp8(v[i]*SCALE, __HIP_SATFINITE, __HIP_E4M3);
            rr[i >> 2] |= byte << ((i & 3) * 8);
        }
        r0 = rr[0]; r1 = rr[1]; r2 = rr[2]; r3 = rr[3];
    }
#endif
    wf8[t] = make_uint4(r0, r1, r2, r3);
}

__device__ __forceinline__ void decode8(unsigned int u, float* e) {
#if HW_FP8
    v2f p0 = __builtin_amdgcn_cvt_pk_f32_fp8((int)u, false);
    v2f p1 = __builtin_amdgcn_cvt_pk_f32_fp8((int)u, true);
    e[0] = p0.x; e[1] = p0.y; e[2] = p1.x; e[3] = p1.y;
#else
    for (int i = 0; i < 4; ++i) {
        __half_raw h = __hip_cvt_fp8_to_halfraw((__hip_fp8_storage_t)((u >> (8*i)) & 0xFF), __HIP_E4M3);
        e[i] = __half2float(__half(h));
    }
#endif
}

// ---------------- main: orphic build + scores + loss ----------------
__global__ __launch_bounds__(256) void orphic_main_fp8(
    const int*   __restrict__ tgt,
    const int*   __restrict__ ctx,
    const int*   __restrict__ neg,
    const float* __restrict__ freq,
    const float* __restrict__ Wf,
    const float* __restrict__ Wr,
    const float* __restrict__ Wi,
    const uint4* __restrict__ wf8,       // [VOCAB][DIM/16] packed fp8 rows (256B each)
    float*       __restrict__ partial)   // [NBLOCKS][2]
{
    const int wave = threadIdx.x >> 6;
    const int lane = threadIdx.x & 63;
    const int g    = lane >> 4;          // score-group 0..3
    const int q    = lane & 15;          // dim-slot in group: dims [q*16, q*16+16)
    const int b    = blockIdx.x * WAVES_PER_BLOCK + wave;

    // ---- orphic[b], dims [q*16, q*16+16) (f32 gathers, 3KB/row) ----
    const int t = tgt[b];
    const float* ft  = Wf + (size_t)t * DIM + q * 16;
    const float* rt  = Wr + (size_t)t * DIM + q * 16;
    const float* it_ = Wi + (size_t)t * DIM + q * 16;
    float o[16];
    {
        float4 f0 = *(const float4*)(ft + 0),  f1 = *(const float4*)(ft + 4);
        float4 f2 = *(const float4*)(ft + 8),  f3 = *(const float4*)(ft + 12);
        float4 r0 = *(const float4*)(rt + 0),  r1 = *(const float4*)(rt + 4);
        float4 r2 = *(const float4*)(rt + 8),  r3 = *(const float4*)(rt + 12);
        float4 w0 = *(const float4*)(it_ + 0), w1 = *(const float4*)(it_ + 4);
        float4 w2 = *(const float4*)(it_ + 8), w3 = *(const float4*)(it_ + 12);
        const float sc = 1.0f / (1.0f + logf(freq[t] + EPS));
        const float ff[16] = {f0.x,f0.y,f0.z,f0.w,f1.x,f1.y,f1.z,f1.w,f2.x,f2.y,f2.z,f2.w,f3.x,f3.y,f3.z,f3.w};
        const float rr[16] = {r0.x,r0.y,r0.z,r0.w,r1.x,r1.y,r1.z,r1.w,r2.x,r2.y,r2.z,r2.w,r3.x,r3.y,r3.z,r3.w};
        const float ww[16] = {w0.x,w0.y,w0.z,w0.w,w1.x,w1.y,w1.z,w1.w,w2.x,w2.y,w2.z,w2.w,w3.x,w3.y,w3.z,w3.w};
        #pragma unroll
        for (int i = 0; i < 16; ++i)
            o[i] = ALPHA * ff[i] + (1.0f - ALPHA) * rr[i] + ww[i] * sc;
    }

    // ---- all 25 token indices, coalesced ----
    int tok = 0;
    if (lane < CTX)       tok = ctx[(size_t)b * CTX + lane];
    else if (lane < NTOK) tok = neg[(size_t)b * NUM_NEG + (lane - CTX)];

    float posacc = 0.0f, negacc = 0.0f;

    #pragma unroll 2
    for (int it = 0; it < 7; ++it) {
        const int j = it * 4 + g;
        const bool valid = (j < NTOK);
        const int jc = valid ? j : (NTOK - 1);
        const int tj = __shfl(tok, jc, 64);

        // fp8 row: this lane's 16 elements = one uint4 (16B)
        const uint4 u = wf8[(size_t)tj * (DIM / 16) + q];
        float e[16];
        decode8(u.x, e + 0);
        decode8(u.y, e + 4);
        decode8(u.z, e + 8);
        decode8(u.w, e + 12);

        float d = 0.0f;
        #pragma unroll
        for (int i = 0; i < 16; ++i) d += o[i] * e[i];

        d += __shfl_xor(d, 1, 64);
        d += __shfl_xor(d, 2, 64);
        d += __shfl_xor(d, 4, 64);
        d += __shfl_xor(d, 8, 64);

        const float s = d * INV_SCALE;
        const float sgn = (jc < CTX) ? -1.0f : 1.0f;
        const float loss = -logf(1.0f / (1.0f + expf(sgn * s)) + EPS);
        if (valid) {
            if (jc < CTX) posacc += loss;
            else          negacc += loss;
        }
    }
    negacc *= (1.0f / NUM_NEG);

    float p = (q == 0) ? posacc : 0.0f;
    float n = (q == 0) ? negacc : 0.0f;
    p += __shfl_xor(p, 16, 64);  p += __shfl_xor(p, 32, 64);
    n += __shfl_xor(n, 16, 64);  n += __shfl_xor(n, 32, 64);

    __shared__ float sp[WAVES_PER_BLOCK];
    __shared__ float sn[WAVES_PER_BLOCK];
    if (lane == 0) { sp[wave] = p; sn[wave] = n; }
    __syncthreads();
    if (threadIdx.x == 0) {
        partial[(size_t)blockIdx.x * 2 + 0] = sp[0] + sp[1] + sp[2] + sp[3];
        partial[(size_t)blockIdx.x * 2 + 1] = sn[0] + sn[1] + sn[2] + sn[3];
    }
}

// ---------------- fallback main (f32 gathers) if ws too small ----------------
__global__ __launch_bounds__(256) void orphic_main_f32(
    const int*   __restrict__ tgt,
    const int*   __restrict__ ctx,
    const int*   __restrict__ neg,
    const float* __restrict__ freq,
    const float* __restrict__ Wf,
    const float* __restrict__ Wr,
    const float* __restrict__ Wi,
    float*       __restrict__ partial)
{
    const int wave = threadIdx.x >> 6;
    const int lane = threadIdx.x & 63;
    const int g    = lane >> 4;
    const int q    = lane & 15;
    const int b    = blockIdx.x * WAVES_PER_BLOCK + wave;

    const int t = tgt[b];
    const float* ft  = Wf + (size_t)t * DIM + q * 16;
    const float* rt  = Wr + (size_t)t * DIM + q * 16;
    const float* it_ = Wi + (size_t)t * DIM + q * 16;
    float o[16];
    {
        const float sc = 1.0f / (1.0f + logf(freq[t] + EPS));
        #pragma unroll
        for (int i = 0; i < 16; ++i)
            o[i] = ALPHA * ft[i] + (1.0f - ALPHA) * rt[i] + it_[i] * sc;
    }

    int tok = 0;
    if (lane < CTX)       tok = ctx[(size_t)b * CTX + lane];
    else if (lane < NTOK) tok = neg[(size_t)b * NUM_NEG + (lane - CTX)];

    float posacc = 0.0f, negacc = 0.0f;
    #pragma unroll 2
    for (int it = 0; it < 7; ++it) {
        const int j = it * 4 + g;
        const bool valid = (j < NTOK);
        const int jc = valid ? j : (NTOK - 1);
        const int tj = __shfl(tok, jc, 64);
        const float* e = Wf + (size_t)tj * DIM + q * 16;
        float d = 0.0f;
        #pragma unroll
        for (int i = 0; i < 16; ++i) d += o[i] * e[i];
        d += __shfl_xor(d, 1, 64);
        d += __shfl_xor(d, 2, 64);
        d += __shfl_xor(d, 4, 64);
        d += __shfl_xor(d, 8, 64);
        const float sgn = (jc < CTX) ? -1.0f : 1.0f;
        const float loss = -logf(1.0f / (1.0f + expf(sgn * d)) + EPS);
        if (valid) {
            if (jc < CTX) posacc += loss;
            else          negacc += loss;
        }
    }
    negacc *= (1.0f / NUM_NEG);

    float p = (q == 0) ? posacc : 0.0f;
    float n = (q == 0) ? negacc : 0.0f;
    p += __shfl_xor(p, 16, 64);  p += __shfl_xor(p, 32, 64);
    n += __shfl_xor(n, 16, 64);  n += __shfl_xor(n, 32, 64);

    __shared__ float sp[WAVES_PER_BLOCK];
    __shared__ float sn[WAVES_PER_BLOCK];
    if (lane == 0) { sp[wave] = p; sn[wave] = n; }
    __syncthreads();
    if (threadIdx.x == 0) {
        partial[(size_t)blockIdx.x * 2 + 0] = sp[0] + sp[1] + sp[2] + sp[3];
        partial[(size_t)blockIdx.x * 2 + 1] = sn[0] + sn[1] + sn[2] + sn[3];
    }
}

__global__ __launch_bounds__(256) void orphic_reduce(
    const float* __restrict__ partial, float* __restrict__ out)
{
    double p = 0.0, n = 0.0;
    for (int i = threadIdx.x; i < NBLOCKS; i += 256) {
        p += (double)partial[(size_t)i * 2 + 0];
        n += (double)partial[(size_t)i * 2 + 1];
    }
    __shared__ double lp[256];
    __shared__ double ln[256];
    lp[threadIdx.x] = p;
    ln[threadIdx.x] = n;
    __syncthreads();
    for (int s = 128; s > 0; s >>= 1) {
        if (threadIdx.x < s) {
            lp[threadIdx.x] += lp[threadIdx.x + s];
            ln[threadIdx.x] += ln[threadIdx.x + s];
        }
        __syncthreads();
    }
    if (threadIdx.x == 0) {
        out[0] = (float)(lp[0] / (double)((size_t)BATCH * CTX) + ln[0]);
    }
}

extern "C" void kernel_launch(void* const* d_in, const int* in_sizes, int n_in,
                              void* d_out, int out_size, void* d_ws, size_t ws_size,
                              hipStream_t stream) {
    const int*   tgt  = (const int*)  d_in[0];
    const int*   ctx  = (const int*)  d_in[1];
    const int*   neg  = (const int*)  d_in[2];
    const float* freq = (const float*)d_in[3];
    const float* Wf   = (const float*)d_in[4];
    const float* Wr   = (const float*)d_in[5];
    const float* Wi   = (const float*)d_in[6];
    float* out = (float*)d_out;

    const size_t tbl_bytes = (size_t)VOCAB * DIM;                  // 25.6 MB fp8 table
    const size_t need = tbl_bytes + (size_t)NBLOCKS * 2 * sizeof(float);

    if (ws_size >= need) {
        uint4* wf8 = (uint4*)d_ws;
        float* partial = (float*)((char*)d_ws + tbl_bytes);        // 25.6e6 % 256 == 0
        convert_wf<<<VOCAB * DIM / 16 / 256, 256, 0, stream>>>(Wf, wf8);   // 6250 blocks
        orphic_main_fp8<<<NBLOCKS, 256, 0, stream>>>(tgt, ctx, neg, freq, Wf, Wr, Wi, wf8, partial);
        orphic_reduce<<<1, 256, 0, stream>>>(partial, out);
    } else {
        float* partial = (float*)d_ws;
        orphic_main_f32<<<NBLOCKS, 256, 0, stream>>>(tgt, ctx, neg, freq, Wf, Wr, Wi, partial);
        orphic_reduce<<<1, 256, 0, stream>>>(partial, out);
    }
}